// Round 3
// baseline (713.847 us; speedup 1.0000x reference)
//
#include <hip/hip_runtime.h>

// Problem constants (fixed in reference setup_inputs)
#define FEAT_C 128
#define NB     4
#define NYv    512
#define NXv    512
#define PX     256                // x-pixels per gather block (half a row)

typedef float vfloat4 __attribute__((ext_vector_type(4)));

// ---------------------------------------------------------------------------
// Kernel 1: scatter voxel ids into idx_map, last-write-wins (max id wins,
// matching numpy fancy-assignment duplicate semantics).
// idx_map pre-initialized to -1 (0xFF memset).
// ---------------------------------------------------------------------------
__global__ void scatter_ids(const int4* __restrict__ coors,
                            int* __restrict__ idx_map, int n) {
    int i = blockIdx.x * blockDim.x + threadIdx.x;
    if (i >= n) return;
    int4 c = coors[i];                       // (b, z, y, x)
    int flat = c.x * (NYv * NXv) + c.z * NXv + c.w;
    atomicMax(&idx_map[flat], i);            // device-scope, cross-XCD safe
}

// ---------------------------------------------------------------------------
// Kernel 2: gather. One block per (b, y, x-half): 256 px x ALL 128 channels.
// Round-3 mechanism under test: XCD-CLUSTERED CACHED WRITES.
//   Evidence (R0-R2): dur insensitive to write-run length 256B->1KiB (-7us)
//   and mildly sensitive to read granule. Hypothesis: the write plateau is
//   caused by ~32k interleaved 1KiB streams defeating MC reordering, not by
//   run length. Fix: consecutive blockIdx round-robin across 8 XCDs, so remap
//   tile = (bid&7)*512 + (bid>>3)  ->  XCD k owns a CONTIGUOUS 512-tile span;
//   its 32 CUs concurrently write 32 consecutive (y,xh) tiles = one 4 MiB
//   contiguous output region (== its L2 size). Plain cached stores (NT
//   removed: write-once data, nothing worth protecting in L2) let the L2
//   accumulate and evict in large near-linear bursts -> fill-like DRAM
//   streams instead of 512 B confetti.
// Reads unchanged: full 512 B voxel row per occupied pixel (optimal granule).
// LDS layout XOR-swizzled: word(p,c) = p*128 + (c ^ 4*((p>>2)&7)).
//   Phase-1 b128 writes: 16 B-aligned, banks uniform 4-deep per half-wave.
//   Phase-2 b32 reads: bank = (c ^ 4*(l&7))&31 -> 4-way = 1.58x (m136);
//   LDS far off the critical path.
// Writes every output element (implicit zero-fill for empty pixels).
// ---------------------------------------------------------------------------
__global__ __launch_bounds__(1024) void gather_bev(
        const float* __restrict__ feat,
        const int* __restrict__ idx_map,
        float* __restrict__ out) {
    __shared__ float tile[PX * FEAT_C];      // 256 px * 128 ch * 4 B = 128 KiB
    __shared__ int sv[PX];                   // 1 KiB

    // XCD-clustered tile remap (bijective on [0,4096)): XCD k sweeps a
    // contiguous span of tiles; tiles ordered (b, y, xh) with xh fastest so
    // a 32-CU sweep generation covers 16 consecutive full y-rows.
    const int bid  = blockIdx.x;
    const int tileid = (bid & 7) * 512 + (bid >> 3);
    const int xh  = tileid & 1;              // x-half
    const int y   = (tileid >> 1) & (NYv - 1);
    const int b   = tileid >> 10;
    const int tid = threadIdx.x;

    if (tid < PX)
        sv[tid] = idx_map[b * (NYv * NXv) + y * NXv + xh * PX + tid];
    __syncthreads();

    // Phase 1: 32 half-waves x 8 pixels each. Per issue a half-wave (32
    // lanes x float4) reads one full 512 B voxel row.
    const int wave = tid >> 6;               // 0..15
    const int lane = tid & 63;
    const int half = lane >> 5;              // 0 or 1
    const int l    = lane & 31;              // float4 slot within a row
    const int hw   = wave * 2 + half;        // half-wave id 0..31
#pragma unroll
    for (int k = 0; k < 8; ++k) {
        const int p = hw * 8 + k;
        const int v = sv[p];
        vfloat4 f = {0.f, 0.f, 0.f, 0.f};
        if (v >= 0) {
            f = ((const vfloat4*)(feat + (size_t)v * FEAT_C))[l];
        }
        const int word = p * FEAT_C + ((4 * l) ^ (4 * ((p >> 2) & 7)));
        *(vfloat4*)&tile[word] = f;          // ds_write_b128, aligned
    }
    __syncthreads();

    // Phase 2: 8192 float4 stores (128 ch x 64 groups of 4 px), 8 iters.
    // Per iteration each half-wave owns ONE channel and stores 512 B
    // contiguous; plain cached stores so the XCD's L2 write-combines the
    // clustered 4 MiB generation before eviction.
    const long plane = (long)NYv * NXv;
    float* out_base = out + (long)b * FEAT_C * plane + (long)y * NXv + xh * PX;
#pragma unroll
    for (int it = 0; it < 8; ++it) {
        const int h2 = it & 1;               // which 128-px half of the tile
        const int cp = it >> 1;              // channel-quarter 0..3
        const int c  = cp * 32 + wave * 2 + half;   // channel 0..127
        const int i0 = 4 * l + 128 * h2;            // x offset in tile
        const int cs = c ^ (4 * (l & 7));           // swizzled channel slot
        vfloat4 r;
        r.x = tile[(i0 + 0) * FEAT_C + cs];
        r.y = tile[(i0 + 1) * FEAT_C + cs];
        r.z = tile[(i0 + 2) * FEAT_C + cs];
        r.w = tile[(i0 + 3) * FEAT_C + cs];
        *(vfloat4*)(out_base + (long)c * plane + i0) = r;   // cached store
    }
}

extern "C" void kernel_launch(void* const* d_in, const int* in_sizes, int n_in,
                              void* d_out, int out_size, void* d_ws, size_t ws_size,
                              hipStream_t stream) {
    const float* feat  = (const float*)d_in[0];
    const int*   coors = (const int*)d_in[1];
    const int n = in_sizes[1] / 4;               // N voxels

    int* idx_map = (int*)d_ws;                   // 4 MiB of ws
    const size_t map_bytes = (size_t)NB * NYv * NXv * sizeof(int);

    // ws is re-poisoned to 0xAA before every timed call -> re-init every call.
    // memset 0xFF == int32 -1 (graph-capturable as a memset node).
    (void)hipMemsetAsync(idx_map, 0xFF, map_bytes, stream);

    scatter_ids<<<(n + 255) / 256, 256, 0, stream>>>(
        (const int4*)coors, idx_map, n);

    const int nblocks = NB * NYv * (NXv / PX);   // 4096
    gather_bev<<<nblocks, 1024, 0, stream>>>(feat, idx_map, (float*)d_out);
}

// Round 4
// 702.055 us; speedup vs baseline: 1.0168x; 1.0168x over previous
//
#include <hip/hip_runtime.h>

// Problem constants (fixed in reference setup_inputs)
#define FEAT_C 128
#define NB     4
#define NYv    512
#define NXv    512
#define PX     256                // x-pixels per gather block (half a row)

typedef float vfloat4 __attribute__((ext_vector_type(4)));

// ---------------------------------------------------------------------------
// SESSION CONCLUSION (R0-R3): dur_us ~700 = ~340 us harness ws-poison fill
// (2.147 GB @ 6.3 TB/s, enqueued upstream on the captured stream — cannot be
// overlapped or removed) + ~45 us reset micro-dispatches + ~12 us scatter +
// ~300 us gather. Gather is invariant (+-6%) under: write-run length 256 B ->
// 2 KiB, NT vs cached stores, XCD-clustered L2 write-combining, 4 blocks/CU
// vs 1 block/CU phase overlap. Read-granule degradation (512 B -> 128 B) cost
// +42 us -> reads already at optimal granule. Remaining structure: mixed
// random-512 B-read + strided-write stream at its practical mixed-stream
// ceiling. This file is the best-measured variant (R2, 700.4 us).
// ---------------------------------------------------------------------------

// ---------------------------------------------------------------------------
// Kernel 1: scatter voxel ids into idx_map, last-write-wins (max id wins,
// matching numpy fancy-assignment duplicate semantics).
// idx_map pre-initialized to -1 (0xFF memset).
// ---------------------------------------------------------------------------
__global__ void scatter_ids(const int4* __restrict__ coors,
                            int* __restrict__ idx_map, int n) {
    int i = blockIdx.x * blockDim.x + threadIdx.x;
    if (i >= n) return;
    int4 c = coors[i];                       // (b, z, y, x)
    int flat = c.x * (NYv * NXv) + c.z * NXv + c.w;
    atomicMax(&idx_map[flat], i);            // device-scope, cross-XCD safe
}

// ---------------------------------------------------------------------------
// Kernel 2: gather. One block per (b, y, x-half): 256 px x ALL 128 channels.
//   reads : full 512 B voxel row per occupied pixel, one half-wave issue,
//           exactly 4 consecutive 128 B lines — no amplification.
//   writes: 1 KiB contiguous per channel per block, NT stores (write-once
//           data; R1/R3 showed cached vs NT is perf-neutral here).
// 128 KiB LDS + 1 KiB sv -> 1 block/CU, 16 waves. Phases alternate
// read-burst/write-burst (R0's 4-block/CU overlap variant: identical perf).
// LDS layout XOR-swizzled: word(p,c) = p*128 + (c ^ 4*((p>>2)&7)).
//   Phase-1 b128 writes: 16 B-aligned, banks uniform 4-deep per half-wave.
//   Phase-2 b32 reads: bank = (c ^ 4*(l&7))&31 -> 4-way = 1.58x (m136);
//   LDS far off the critical path.
// Writes every output element (implicit zero-fill for empty pixels).
// ---------------------------------------------------------------------------
__global__ __launch_bounds__(1024) void gather_bev(
        const float* __restrict__ feat,
        const int* __restrict__ idx_map,
        float* __restrict__ out) {
    __shared__ float tile[PX * FEAT_C];      // 256 px * 128 ch * 4 B = 128 KiB
    __shared__ int sv[PX];                   // 1 KiB

    const int bid = blockIdx.x;
    const int xh  = bid & 1;                 // x-half (siblings co-resident)
    const int y   = (bid >> 1) & (NYv - 1);
    const int b   = bid >> 10;
    const int tid = threadIdx.x;

    if (tid < PX)
        sv[tid] = idx_map[b * (NYv * NXv) + y * NXv + xh * PX + tid];
    __syncthreads();

    // Phase 1: 32 half-waves x 8 pixels each. Per issue a half-wave (32
    // lanes x float4) reads one full 512 B voxel row.
    const int wave = tid >> 6;               // 0..15
    const int lane = tid & 63;
    const int half = lane >> 5;              // 0 or 1
    const int l    = lane & 31;              // float4 slot within a row
    const int hw   = wave * 2 + half;        // half-wave id 0..31
#pragma unroll
    for (int k = 0; k < 8; ++k) {
        const int p = hw * 8 + k;
        const int v = sv[p];
        vfloat4 f = {0.f, 0.f, 0.f, 0.f};
        if (v >= 0) {
            f = ((const vfloat4*)(feat + (size_t)v * FEAT_C))[l];
        }
        const int word = p * FEAT_C + ((4 * l) ^ (4 * ((p >> 2) & 7)));
        *(vfloat4*)&tile[word] = f;          // ds_write_b128, aligned
    }
    __syncthreads();

    // Phase 2: 8192 float4 stores (128 ch x 64 groups of 4 px), 8 iters.
    // Per iteration each half-wave owns ONE channel and stores 512 B
    // contiguous (lanes 0..31 -> x offsets 4l..4l+3 within a 128-px half).
    const long plane = (long)NYv * NXv;
    float* out_base = out + (long)b * FEAT_C * plane + (long)y * NXv + xh * PX;
#pragma unroll
    for (int it = 0; it < 8; ++it) {
        const int h2 = it & 1;               // which 128-px half of the tile
        const int cp = it >> 1;              // channel-quarter 0..3
        const int c  = cp * 32 + wave * 2 + half;   // channel 0..127
        const int i0 = 4 * l + 128 * h2;            // x offset in tile
        const int cs = c ^ (4 * (l & 7));           // swizzled channel slot
        vfloat4 r;
        r.x = tile[(i0 + 0) * FEAT_C + cs];
        r.y = tile[(i0 + 1) * FEAT_C + cs];
        r.z = tile[(i0 + 2) * FEAT_C + cs];
        r.w = tile[(i0 + 3) * FEAT_C + cs];
        __builtin_nontemporal_store(r, (vfloat4*)(out_base + (long)c * plane + i0));
    }
}

extern "C" void kernel_launch(void* const* d_in, const int* in_sizes, int n_in,
                              void* d_out, int out_size, void* d_ws, size_t ws_size,
                              hipStream_t stream) {
    const float* feat  = (const float*)d_in[0];
    const int*   coors = (const int*)d_in[1];
    const int n = in_sizes[1] / 4;               // N voxels

    int* idx_map = (int*)d_ws;                   // 4 MiB of ws
    const size_t map_bytes = (size_t)NB * NYv * NXv * sizeof(int);

    // ws is re-poisoned to 0xAA before every timed call -> re-init every call.
    // memset 0xFF == int32 -1 (graph-capturable as a memset node).
    (void)hipMemsetAsync(idx_map, 0xFF, map_bytes, stream);

    scatter_ids<<<(n + 255) / 256, 256, 0, stream>>>(
        (const int4*)coors, idx_map, n);

    const int nblocks = NB * NYv * (NXv / PX);   // 4096
    gather_bev<<<nblocks, 1024, 0, stream>>>(feat, idx_map, (float*)d_out);
}